// Round 1
// baseline (2479.540 us; speedup 1.0000x reference)
//
#include <hip/hip_runtime.h>

#define NN    48
#define DD    16
#define HH    256
#define EE    2256
#define BB    32
#define NPRED 8
#define CH    16   // edge chunk per type in encoder

// ---------------------------------------------------------------------------
// Setup: copy initial state, build per-(b,tgt) incoming-edge lists grouped by
// type (type-0 edges dropped -- they contribute exactly zero through et mask).
// Sequential scan per (b,n) => deterministic order, no atomics.
// Edge index closed form (np.nonzero(ones-eye), row-major):
//   e(src,tgt) = src*47 + (tgt - (tgt>src ? 1 : 0))
// ---------------------------------------------------------------------------
__global__ __launch_bounds__(256) void k_setup(
    const float* __restrict__ time_segs,
    const float* __restrict__ edge_types,
    float* __restrict__ state,
    int* __restrict__ lists,
    int* __restrict__ counts)
{
    const int tid = blockIdx.x * 256 + threadIdx.x;   // 0..1535 = b*NN+n
    // state init: state[b,n,d] = time_segs[b,0,n,d]
    for (int i = tid; i < BB*NN*DD; i += BB*NN)
        state[i] = time_segs[i];

    const int b = tid / NN;
    const int n = tid % NN;
    int* lst = lists + tid * 47;
    int c = 0;
    // pass 1: type 1 (-> weight slot 0)
    for (int s = 0; s < NN; ++s) {
        if (s == n) continue;
        const int e = s * 47 + (n > s ? n - 1 : n);
        if (edge_types[((size_t)b*EE + e)*3 + 1] > 0.5f) lst[c++] = s;
    }
    const int c1 = c;
    // pass 2: type 2 (-> weight slot 1)
    for (int s = 0; s < NN; ++s) {
        if (s == n) continue;
        const int e = s * 47 + (n > s ? n - 1 : n);
        if (edge_types[((size_t)b*EE + e)*3 + 2] > 0.5f) lst[c++] = s;
    }
    counts[tid*2 + 0] = c1;
    counts[tid*2 + 1] = c - c1;
    for (int i = c; i < 47; ++i) lst[i] = 0;   // pad: valid (garbage-masked) index
}

// ---------------------------------------------------------------------------
// Encoder + scatter: one block per (b, tgt node). Computes
//   node_msg[b,n,:] = sum over active incoming edges of
//       relu( relu([st[src],st[n]] @ W1[t] + b1[t]) @ W2[t] + b2[t] )
// Thread = output column h. h1 chunk staged in LDS; all LDS reads broadcast.
// ---------------------------------------------------------------------------
__global__ __launch_bounds__(256) void k_enc(
    const float* __restrict__ state,
    const int*   __restrict__ lists,
    const int*   __restrict__ counts,
    const float* __restrict__ W1,   // (2, 32, 256)
    const float* __restrict__ b1,   // (2, 256)
    const float* __restrict__ W2,   // (2, 256, 256)
    const float* __restrict__ b2,   // (2, 256)
    float* __restrict__ node_msg)
{
    const int bid = blockIdx.x;          // b*NN + n
    const int n   = bid % NN;
    const int b   = bid / NN;
    const int h   = threadIdx.x;         // 0..255

    __shared__ float st[NN*DD];          // 3 KB: full state[b]
    __shared__ float h1[CH][HH];         // 16 KB
    __shared__ int   lst_s[48];

    for (int i = threadIdx.x; i < NN*DD; i += 256)
        st[i] = state[(size_t)b*NN*DD + i];
    if (threadIdx.x < 47)
        lst_s[threadIdx.x] = lists[bid*47 + threadIdx.x];
    const int c1 = counts[bid*2 + 0];
    const int c2 = counts[bid*2 + 1];
    __syncthreads();

    const float4* st4 = (const float4*)st;
    float agg = 0.f;

    for (int t = 0; t < 2; ++t) {
        const int base = t ? c1 : 0;
        const int cnt  = t ? c2 : c1;
        if (cnt == 0) continue;
        const float* W1t = W1 + (size_t)t * (2*DD*HH);
        const float* W2t = W2 + (size_t)t * (HH*HH);
        const float  bias2 = b2[t*HH + h];

        // hoist src-half W1 column h; fold bias1 + tgt-half (same for all edges)
        float w1r[DD];
        #pragma unroll
        for (int f = 0; f < DD; ++f) w1r[f] = W1t[f*HH + h];
        float accT = b1[t*HH + h];
        #pragma unroll
        for (int f = 0; f < DD; ++f) accT += st[n*DD + f] * W1t[(DD+f)*HH + h];

        for (int cs = 0; cs < cnt; cs += CH) {
            // ---- layer 1 (relu) ----
            float acc[CH];
            #pragma unroll
            for (int e = 0; e < CH; ++e) {
                int idx = base + cs + e; if (idx > 46) idx = 46;   // clamp pad
                const int s = lst_s[idx];
                const float4 r0 = st4[s*4+0], r1 = st4[s*4+1];
                const float4 r2 = st4[s*4+2], r3 = st4[s*4+3];
                float a = accT;
                a += r0.x*w1r[0]  + r0.y*w1r[1]  + r0.z*w1r[2]  + r0.w*w1r[3];
                a += r1.x*w1r[4]  + r1.y*w1r[5]  + r1.z*w1r[6]  + r1.w*w1r[7];
                a += r2.x*w1r[8]  + r2.y*w1r[9]  + r2.z*w1r[10] + r2.w*w1r[11];
                a += r3.x*w1r[12] + r3.y*w1r[13] + r3.z*w1r[14] + r3.w*w1r[15];
                acc[e] = fmaxf(a, 0.f);
            }
            __syncthreads();               // previous chunk's layer-2 reads done
            #pragma unroll
            for (int e = 0; e < CH; ++e) h1[e][h] = acc[e];
            __syncthreads();               // h1 ready

            // ---- layer 2 ----
            float acc2[CH];
            #pragma unroll
            for (int e = 0; e < CH; ++e) acc2[e] = 0.f;
            #pragma unroll 2
            for (int g4 = 0; g4 < HH/4; ++g4) {
                const float w0  = W2t[(g4*4+0)*HH + h];
                const float w1_ = W2t[(g4*4+1)*HH + h];
                const float w2_ = W2t[(g4*4+2)*HH + h];
                const float w3  = W2t[(g4*4+3)*HH + h];
                #pragma unroll
                for (int e = 0; e < CH; ++e) {
                    const float4 a = *(const float4*)&h1[e][g4*4];
                    acc2[e] = fmaf(a.x, w0, fmaf(a.y, w1_,
                              fmaf(a.z, w2_, fmaf(a.w, w3, acc2[e]))));
                }
            }
            #pragma unroll
            for (int e = 0; e < CH; ++e)
                if (cs + e < cnt) agg += fmaxf(acc2[e] + bias2, 0.f);
        }
    }
    node_msg[(size_t)bid*HH + h] = agg;
}

// ---------------------------------------------------------------------------
// Decoder: block per (b, 16-row chunk). Fused 272->256->256->16 + residual.
// Writes updated state and the step's output slice.
// ---------------------------------------------------------------------------
__global__ __launch_bounds__(256) void k_dec(
    float* __restrict__ state,
    const float* __restrict__ node_msg,
    const float* __restrict__ W1, const float* __restrict__ b1,  // (272,256)
    const float* __restrict__ W2, const float* __restrict__ b2,  // (256,256)
    const float* __restrict__ W3, const float* __restrict__ b3,  // (256,16)
    float* __restrict__ out, int step)
{
    const int b    = blockIdx.x / 3;
    const int row0 = (blockIdx.x % 3) * 16;
    const int h    = threadIdx.x;

    __shared__ float in_s[16][272];   // node_in; later reused as d2
    __shared__ float d1_s[16][256];

    for (int i = threadIdx.x; i < 16*272; i += 256) {
        const int m = i / 272, k = i % 272;
        const int r = row0 + m;
        in_s[m][k] = (k < DD)
            ? state[((size_t)b*NN + r)*DD + k]
            : node_msg[((size_t)b*NN + r)*HH + (k - DD)];
    }
    __syncthreads();

    float acc[16];
    // ---- layer 1: 272 -> 256, relu ----
    {
        const float bias = b1[h];
        #pragma unroll
        for (int m = 0; m < 16; ++m) acc[m] = bias;
        #pragma unroll 2
        for (int k4 = 0; k4 < 272/4; ++k4) {
            const float w0  = W1[(k4*4+0)*HH + h];
            const float w1_ = W1[(k4*4+1)*HH + h];
            const float w2_ = W1[(k4*4+2)*HH + h];
            const float w3  = W1[(k4*4+3)*HH + h];
            #pragma unroll
            for (int m = 0; m < 16; ++m) {
                const float4 a = *(const float4*)&in_s[m][k4*4];
                acc[m] = fmaf(a.x, w0, fmaf(a.y, w1_,
                         fmaf(a.z, w2_, fmaf(a.w, w3, acc[m]))));
            }
        }
        #pragma unroll
        for (int m = 0; m < 16; ++m) d1_s[m][h] = fmaxf(acc[m], 0.f);
    }
    __syncthreads();
    // ---- layer 2: 256 -> 256, relu -> overwrite in_s as d2 ----
    {
        const float bias = b2[h];
        #pragma unroll
        for (int m = 0; m < 16; ++m) acc[m] = bias;
        #pragma unroll 2
        for (int k4 = 0; k4 < HH/4; ++k4) {
            const float w0  = W2[(k4*4+0)*HH + h];
            const float w1_ = W2[(k4*4+1)*HH + h];
            const float w2_ = W2[(k4*4+2)*HH + h];
            const float w3  = W2[(k4*4+3)*HH + h];
            #pragma unroll
            for (int m = 0; m < 16; ++m) {
                const float4 a = *(const float4*)&d1_s[m][k4*4];
                acc[m] = fmaf(a.x, w0, fmaf(a.y, w1_,
                         fmaf(a.z, w2_, fmaf(a.w, w3, acc[m]))));
            }
        }
        __syncthreads();   // all layer-2 d1 reads done before in_s overwrite? (layer1 reads done pre-d1-barrier; d1 reads use d1_s) -- safe
        #pragma unroll
        for (int m = 0; m < 16; ++m) in_s[m][h] = fmaxf(acc[m], 0.f);
    }
    __syncthreads();
    // ---- layer 3: 256 -> 16, residual, write state + out ----
    {
        const int m = h >> 4;
        const int c = h & 15;
        float a3 = b3[c];
        #pragma unroll 4
        for (int k4 = 0; k4 < HH/4; ++k4) {
            const float4 a = *(const float4*)&in_s[m][k4*4];
            a3 += a.x*W3[(k4*4+0)*16 + c] + a.y*W3[(k4*4+1)*16 + c]
                + a.z*W3[(k4*4+2)*16 + c] + a.w*W3[(k4*4+3)*16 + c];
        }
        const int r = row0 + m;
        const float v = state[((size_t)b*NN + r)*DD + c] + a3;
        state[((size_t)b*NN + r)*DD + c] = v;
        out[(((size_t)b*NPRED + step)*NN + r)*DD + c] = v;
    }
}

// ---------------------------------------------------------------------------
extern "C" void kernel_launch(void* const* d_in, const int* in_sizes, int n_in,
                              void* d_out, int out_size, void* d_ws, size_t ws_size,
                              hipStream_t stream)
{
    const float* time_segs  = (const float*)d_in[0];
    const float* edge_types = (const float*)d_in[1];
    // d_in[2] = src_idx, d_in[3] = tgt_idx (closed-form used instead)
    const float* enc_W1 = (const float*)d_in[4];
    const float* enc_b1 = (const float*)d_in[5];
    const float* enc_W2 = (const float*)d_in[6];
    const float* enc_b2 = (const float*)d_in[7];
    const float* dec_W1 = (const float*)d_in[8];
    const float* dec_b1 = (const float*)d_in[9];
    const float* dec_W2 = (const float*)d_in[10];
    const float* dec_b2 = (const float*)d_in[11];
    const float* out_W  = (const float*)d_in[12];
    const float* out_b  = (const float*)d_in[13];
    float* out = (float*)d_out;

    // workspace layout (~1.97 MB)
    float* state    = (float*)d_ws;                 // 24576 f
    float* node_msg = state + BB*NN*DD;             // 393216 f
    int*   lists    = (int*)(node_msg + BB*NN*HH);  // 72192 i
    int*   counts   = lists + BB*NN*47;             // 3072 i

    k_setup<<<6, 256, 0, stream>>>(time_segs, edge_types, state, lists, counts);
    for (int stp = 0; stp < NPRED; ++stp) {
        k_enc<<<BB*NN, 256, 0, stream>>>(state, lists, counts,
                                         enc_W1, enc_b1, enc_W2, enc_b2, node_msg);
        k_dec<<<BB*3, 256, 0, stream>>>(state, node_msg,
                                        dec_W1, dec_b1, dec_W2, dec_b2,
                                        out_W, out_b, out, stp);
    }
}

// Round 2
// 1607.819 us; speedup vs baseline: 1.5422x; 1.5422x over previous
//
#include <hip/hip_runtime.h>

#define NN    48
#define DD    16
#define HH    256
#define EE    2256
#define BB    32
#define NPRED 8
#define LSTR  56   // per-(b,n) list stride: c1 + ceil(c2/8)*8 <= 47+8 = 55

// ---------------------------------------------------------------------------
// Setup (once): state init, W1 transpose (W1T[t][h][f], f0..15=src,16..31=tgt),
// per-(b,n) incoming-edge lists grouped by type. Deterministic, no atomics.
// Edge index closed form: e(src,tgt) = src*47 + (tgt - (tgt>src))
// ---------------------------------------------------------------------------
__global__ __launch_bounds__(256) void k_setup(
    const float* __restrict__ time_segs,
    const float* __restrict__ edge_types,
    const float* __restrict__ W1,      // (2,32,256)
    float* __restrict__ state,
    float* __restrict__ W1T,           // (2,256,32)
    int* __restrict__ lists,
    int* __restrict__ counts)
{
    const int tid = blockIdx.x * 256 + threadIdx.x;   // 0..1535
    for (int i = tid; i < BB*NN*DD; i += BB*NN)
        state[i] = time_segs[i];
    for (int i = tid; i < 2*HH*32; i += BB*NN) {
        const int t = i >> 13, r = i & 8191, h = r >> 5, f = r & 31;
        W1T[i] = W1[(t*32 + f)*HH + h];
    }
    const int b = tid / NN;
    const int n = tid % NN;
    int* lst = lists + tid * LSTR;
    int c = 0;
    for (int s = 0; s < NN; ++s) {
        if (s == n) continue;
        const int e = s * 47 + (n > s ? n - 1 : n);
        if (edge_types[((size_t)b*EE + e)*3 + 1] > 0.5f) lst[c++] = s;
    }
    const int c1 = c;
    for (int s = 0; s < NN; ++s) {
        if (s == n) continue;
        const int e = s * 47 + (n > s ? n - 1 : n);
        if (edge_types[((size_t)b*EE + e)*3 + 2] > 0.5f) lst[c++] = s;
    }
    counts[tid*2 + 0] = c1;
    counts[tid*2 + 1] = c - c1;
    for (int i = c; i < LSTR; ++i) lst[i] = 0;   // pads: valid index, masked later
}

// ---------------------------------------------------------------------------
// Encoder edge-group: build h1 (ES edges x 256) in LDS via outer-product from
// state + W1T, then GEMM vs W2 with NI=2 register blocking, masked aggregate.
// ---------------------------------------------------------------------------
template<int ES>
__device__ __forceinline__ void enc_group(
    int goff, int lim,
    const int* __restrict__ lst_s, const float4* __restrict__ st4,
    const float* __restrict__ W1Tt, const float* __restrict__ W2t,
    float v0, float v1, float b20, float b21,
    float (*h1)[HH], int c, int c2, float& agg0, float& agg1)
{
    // ---- build h1 (pre-relu accs start at tgt-half+bias v0/v1) ----
    float u0[ES], u1[ES];
    int src[ES];
    #pragma unroll
    for (int e = 0; e < ES; ++e) {
        src[e] = lst_s[goff + e];
        u0[e] = v0; u1[e] = v1;
    }
    const float4* w1c  = (const float4*)(W1Tt + c  * 32);
    const float4* w1c2 = (const float4*)(W1Tt + c2 * 32);
    #pragma unroll
    for (int f4 = 0; f4 < 4; ++f4) {
        const float4 wa = w1c[f4], wb = w1c2[f4];
        #pragma unroll
        for (int e = 0; e < ES; ++e) {
            const float4 s4 = st4[src[e]*4 + f4];
            u0[e] = fmaf(s4.x, wa.x, fmaf(s4.y, wa.y, fmaf(s4.z, wa.z, fmaf(s4.w, wa.w, u0[e]))));
            u1[e] = fmaf(s4.x, wb.x, fmaf(s4.y, wb.y, fmaf(s4.z, wb.z, fmaf(s4.w, wb.w, u1[e]))));
        }
    }
    #pragma unroll
    for (int e = 0; e < ES; ++e) {
        h1[e][c]  = fmaxf(u0[e], 0.f);
        h1[e][c2] = fmaxf(u1[e], 0.f);
    }
    __syncthreads();

    // ---- GEMM: acc[ES][2] over k=256, W2 original [k][h] layout ----
    float a0[ES], a1[ES];
    #pragma unroll
    for (int e = 0; e < ES; ++e) { a0[e] = 0.f; a1[e] = 0.f; }
    #pragma unroll 2
    for (int k4 = 0; k4 < HH/4; ++k4) {
        const float* wr = W2t + (k4*4)*HH;
        const float w00 = wr[c],        w01 = wr[c2];
        const float w10 = wr[HH+c],     w11 = wr[HH+c2];
        const float w20 = wr[2*HH+c],   w21 = wr[2*HH+c2];
        const float w30 = wr[3*HH+c],   w31 = wr[3*HH+c2];
        #pragma unroll
        for (int e = 0; e < ES; ++e) {
            const float4 h = *(const float4*)&h1[e][k4*4];
            a0[e] = fmaf(h.x,w00, fmaf(h.y,w10, fmaf(h.z,w20, fmaf(h.w,w30, a0[e]))));
            a1[e] = fmaf(h.x,w01, fmaf(h.y,w11, fmaf(h.z,w21, fmaf(h.w,w31, a1[e]))));
        }
    }
    #pragma unroll
    for (int e = 0; e < ES; ++e) {
        if (e < lim) {
            agg0 += fmaxf(a0[e] + b20, 0.f);
            agg1 += fmaxf(a1[e] + b21, 0.f);
        }
    }
    __syncthreads();
}

__global__ __launch_bounds__(128, 3) void k_enc(
    const float* __restrict__ state,
    const int*   __restrict__ lists,
    const int*   __restrict__ counts,
    const float* __restrict__ W1T,   // (2,256,32)
    const float* __restrict__ b1,    // (2,256)
    const float* __restrict__ W2,    // (2,256,256)
    const float* __restrict__ b2,    // (2,256)
    float* __restrict__ node_msg)
{
    const int bid = blockIdx.x;      // b*NN + n
    const int n   = bid % NN;
    const int b   = bid / NN;
    const int c   = threadIdx.x;     // 0..127
    const int c2  = c + 128;

    __shared__ float st[NN*DD];      // 3 KB
    __shared__ float h1[16][HH];     // 16 KB
    __shared__ int   lst_s[LSTR];

    for (int i = threadIdx.x; i < NN*DD; i += 128)
        st[i] = state[(size_t)b*NN*DD + i];
    if (threadIdx.x < LSTR)
        lst_s[threadIdx.x] = lists[bid*LSTR + threadIdx.x];
    const int c1 = counts[bid*2 + 0];
    const int cB = counts[bid*2 + 1];
    __syncthreads();

    const float4* st4 = (const float4*)st;
    float agg0 = 0.f, agg1 = 0.f;

    #pragma unroll 1
    for (int t = 0; t < 2; ++t) {
        const int cnt   = t ? cB : c1;
        const int tbase = t ? c1 : 0;
        if (cnt == 0) continue;
        const float* W1Tt = W1T + t*HH*32;
        const float* W2t  = W2  + (size_t)t*HH*HH;
        const float  b20  = b2[t*HH + c];
        const float  b21  = b2[t*HH + c2];

        // tgt-half + bias1 folded per thread
        float v0 = b1[t*HH + c], v1 = b1[t*HH + c2];
        const float4* w1r0 = (const float4*)(W1Tt + c*32  + 16);
        const float4* w1r1 = (const float4*)(W1Tt + c2*32 + 16);
        #pragma unroll
        for (int f4 = 0; f4 < 4; ++f4) {
            const float4 s4 = st4[n*4 + f4];
            const float4 a = w1r0[f4], bq = w1r1[f4];
            v0 = fmaf(s4.x,a.x,  fmaf(s4.y,a.y,  fmaf(s4.z,a.z,  fmaf(s4.w,a.w,  v0))));
            v1 = fmaf(s4.x,bq.x, fmaf(s4.y,bq.y, fmaf(s4.z,bq.z, fmaf(s4.w,bq.w, v1))));
        }

        const int slots = ((cnt + 7) >> 3) << 3;
        int off = 0;
        while (off < slots) {
            if (slots - off >= 16) {
                enc_group<16>(tbase + off, cnt - off, lst_s, st4, W1Tt, W2t,
                              v0, v1, b20, b21, h1, c, c2, agg0, agg1);
                off += 16;
            } else {
                enc_group<8>(tbase + off, cnt - off, lst_s, st4, W1Tt, W2t,
                             v0, v1, b20, b21, h1, c, c2, agg0, agg1);
                off += 8;
            }
        }
    }
    node_msg[(size_t)bid*HH + c]  = agg0;
    node_msg[(size_t)bid*HH + c2] = agg1;
}

// ---------------------------------------------------------------------------
// Decoder: 4 rows/block (384 blocks), 128 threads, NI=2. Fused 272->256->256
// ->16 + residual. Weights in original [k][h] layout (coalesced scalar loads).
// ---------------------------------------------------------------------------
__global__ __launch_bounds__(128, 3) void k_dec(
    float* __restrict__ state,
    const float* __restrict__ node_msg,
    const float* __restrict__ W1, const float* __restrict__ b1,  // (272,256)
    const float* __restrict__ W2, const float* __restrict__ b2,  // (256,256)
    const float* __restrict__ W3, const float* __restrict__ b3,  // (256,16)
    float* __restrict__ out, int step)
{
    const int b    = blockIdx.x / 12;
    const int row0 = (blockIdx.x % 12) * 4;
    const int c    = threadIdx.x, c2 = c + 128;

    __shared__ float in_s[4][272];   // node_in; reused for d2
    __shared__ float d1[4][HH];

    for (int i = threadIdx.x; i < 4*272; i += 128) {
        const int m = i / 272, k = i % 272;
        const int r = row0 + m;
        in_s[m][k] = (k < DD)
            ? state[((size_t)b*NN + r)*DD + k]
            : node_msg[((size_t)b*NN + r)*HH + (k - DD)];
    }
    __syncthreads();

    float a0[4], a1[4];
    // ---- L1: 272 -> 256, relu ----
    {
        const float bb0 = b1[c], bb1 = b1[c2];
        #pragma unroll
        for (int m = 0; m < 4; ++m) { a0[m] = bb0; a1[m] = bb1; }
        #pragma unroll 2
        for (int k4 = 0; k4 < 68; ++k4) {
            const float* wr = W1 + (k4*4)*HH;
            const float w00=wr[c],      w01=wr[c2];
            const float w10=wr[HH+c],   w11=wr[HH+c2];
            const float w20=wr[2*HH+c], w21=wr[2*HH+c2];
            const float w30=wr[3*HH+c], w31=wr[3*HH+c2];
            #pragma unroll
            for (int m = 0; m < 4; ++m) {
                const float4 h = *(const float4*)&in_s[m][k4*4];
                a0[m] = fmaf(h.x,w00, fmaf(h.y,w10, fmaf(h.z,w20, fmaf(h.w,w30, a0[m]))));
                a1[m] = fmaf(h.x,w01, fmaf(h.y,w11, fmaf(h.z,w21, fmaf(h.w,w31, a1[m]))));
            }
        }
        #pragma unroll
        for (int m = 0; m < 4; ++m) {
            d1[m][c]  = fmaxf(a0[m], 0.f);
            d1[m][c2] = fmaxf(a1[m], 0.f);
        }
    }
    __syncthreads();
    // ---- L2: 256 -> 256, relu; d2 overwrites in_s (distinct from d1) ----
    {
        const float bb0 = b2[c], bb1 = b2[c2];
        #pragma unroll
        for (int m = 0; m < 4; ++m) { a0[m] = bb0; a1[m] = bb1; }
        #pragma unroll 2
        for (int k4 = 0; k4 < 64; ++k4) {
            const float* wr = W2 + (k4*4)*HH;
            const float w00=wr[c],      w01=wr[c2];
            const float w10=wr[HH+c],   w11=wr[HH+c2];
            const float w20=wr[2*HH+c], w21=wr[2*HH+c2];
            const float w30=wr[3*HH+c], w31=wr[3*HH+c2];
            #pragma unroll
            for (int m = 0; m < 4; ++m) {
                const float4 h = *(const float4*)&d1[m][k4*4];
                a0[m] = fmaf(h.x,w00, fmaf(h.y,w10, fmaf(h.z,w20, fmaf(h.w,w30, a0[m]))));
                a1[m] = fmaf(h.x,w01, fmaf(h.y,w11, fmaf(h.z,w21, fmaf(h.w,w31, a1[m]))));
            }
        }
        #pragma unroll
        for (int m = 0; m < 4; ++m) {
            in_s[m][c]  = fmaxf(a0[m], 0.f);
            in_s[m][c2] = fmaxf(a1[m], 0.f);
        }
    }
    __syncthreads();
    // ---- L3: 256 -> 16, residual, write state + out ----
    if (threadIdx.x < 64) {
        const int m = threadIdx.x >> 4, cc = threadIdx.x & 15;
        float a = b3[cc];
        #pragma unroll 4
        for (int k4 = 0; k4 < 64; ++k4) {
            const float4 h = *(const float4*)&in_s[m][k4*4];
            a += h.x*W3[(k4*4+0)*16+cc] + h.y*W3[(k4*4+1)*16+cc]
               + h.z*W3[(k4*4+2)*16+cc] + h.w*W3[(k4*4+3)*16+cc];
        }
        const int r = row0 + m;
        const float v = state[((size_t)b*NN + r)*DD + cc] + a;
        state[((size_t)b*NN + r)*DD + cc] = v;
        out[(((size_t)b*NPRED + step)*NN + r)*DD + cc] = v;
    }
}

// ---------------------------------------------------------------------------
extern "C" void kernel_launch(void* const* d_in, const int* in_sizes, int n_in,
                              void* d_out, int out_size, void* d_ws, size_t ws_size,
                              hipStream_t stream)
{
    const float* time_segs  = (const float*)d_in[0];
    const float* edge_types = (const float*)d_in[1];
    const float* enc_W1 = (const float*)d_in[4];
    const float* enc_b1 = (const float*)d_in[5];
    const float* enc_W2 = (const float*)d_in[6];
    const float* enc_b2 = (const float*)d_in[7];
    const float* dec_W1 = (const float*)d_in[8];
    const float* dec_b1 = (const float*)d_in[9];
    const float* dec_W2 = (const float*)d_in[10];
    const float* dec_b2 = (const float*)d_in[11];
    const float* out_W  = (const float*)d_in[12];
    const float* out_b  = (const float*)d_in[13];
    float* out = (float*)d_out;

    // workspace layout (~2.1 MB)
    float* state    = (float*)d_ws;                    // 24576 f
    float* node_msg = state + BB*NN*DD;                // 393216 f
    float* W1T      = node_msg + BB*NN*HH;             // 16384 f
    int*   lists    = (int*)(W1T + 2*HH*32);           // 86016 i
    int*   counts   = lists + BB*NN*LSTR;              // 3072 i

    k_setup<<<6, 256, 0, stream>>>(time_segs, edge_types, enc_W1,
                                   state, W1T, lists, counts);
    for (int stp = 0; stp < NPRED; ++stp) {
        k_enc<<<BB*NN, 128, 0, stream>>>(state, lists, counts,
                                         W1T, enc_b1, enc_W2, enc_b2, node_msg);
        k_dec<<<BB*12, 128, 0, stream>>>(state, node_msg,
                                         dec_W1, dec_b1, dec_W2, dec_b2,
                                         out_W, out_b, out, stp);
    }
}

// Round 4
// 1378.459 us; speedup vs baseline: 1.7988x; 1.1664x over previous
//
#include <hip/hip_runtime.h>

#define NN    48
#define DD    16
#define HH    256
#define EE    2256
#define BB    32
#define NPRED 8
#define LSTR  56
#define APL_STRIDE 80                 // bytes per A-plane row (5x16B, bijective, 2-way banks)
#define APL_PLANE  (128*APL_STRIDE)   // 10240 B per plane

typedef __attribute__((ext_vector_type(4))) float f32x4;
typedef __attribute__((ext_vector_type(8))) short short8;

__device__ __forceinline__ float bf2f(unsigned short h) {
    union { unsigned u; float f; } v; v.u = ((unsigned)h) << 16; return v.f;
}
__device__ __forceinline__ unsigned short f2bf(float x) {
    union { float f; unsigned u; } v; v.f = x;
    unsigned r = v.u + 0x7fffu + ((v.u >> 16) & 1u);
    return (unsigned short)(r >> 16);
}

// ---------------------------------------------------------------------------
// Setup: state copy, W1 transpose, type-grouped edge lists, W2 split into
// 3 bf16 planes in MFMA B-fragment order (unchanged from R3 — verified logic).
// ---------------------------------------------------------------------------
__global__ __launch_bounds__(256) void k_setup(
    const float* __restrict__ time_segs,
    const float* __restrict__ edge_types,
    const float* __restrict__ W1,      // (2,32,256)
    const float* __restrict__ W2,      // (2,256,256)
    float* __restrict__ state,
    float* __restrict__ W1T,           // (2,256,32)
    unsigned short* __restrict__ W2f,  // 393216
    int* __restrict__ lists,
    int* __restrict__ counts)
{
    const int tid = blockIdx.x * 256 + threadIdx.x;   // 0..1535
    for (int i = tid; i < BB*NN*DD; i += BB*NN)
        state[i] = time_segs[i];
    for (int i = tid; i < 2*HH*32; i += BB*NN) {
        const int t = i >> 13, r = i & 8191, h = r >> 5, f = r & 31;
        W1T[i] = W1[(t*32 + f)*HH + h];
    }
    for (int i = tid; i < 2*8*16*64*8; i += BB*NN) {
        const int j  = i & 7, l = (i >> 3) & 63, nt = (i >> 9) & 15;
        const int kt = (i >> 13) & 7, t = (i >> 16) & 1;
        const int k = kt*32 + ((l >> 4) << 3) + j;
        const int n = nt*16 + (l & 15);
        const float w = W2[((size_t)t*HH + k)*HH + n];
        const unsigned short h0 = f2bf(w);  const float r1 = w  - bf2f(h0);
        const unsigned short h1 = f2bf(r1); const float r2 = r1 - bf2f(h1);
        const unsigned short h2 = f2bf(r2);
        const size_t rest = (size_t)kt*8192 + nt*512 + l*8 + j;
        W2f[(size_t)(t*3+0)*65536 + rest] = h0;
        W2f[(size_t)(t*3+1)*65536 + rest] = h1;
        W2f[(size_t)(t*3+2)*65536 + rest] = h2;
    }
    const int b = tid / NN;
    const int n = tid % NN;
    int* lst = lists + tid * LSTR;
    int c = 0;
    for (int s = 0; s < NN; ++s) {
        if (s == n) continue;
        const int e = s * 47 + (n > s ? n - 1 : n);
        if (edge_types[((size_t)b*EE + e)*3 + 1] > 0.5f) lst[c++] = s;
    }
    const int c1 = c;
    for (int s = 0; s < NN; ++s) {
        if (s == n) continue;
        const int e = s * 47 + (n > s ? n - 1 : n);
        if (edge_types[((size_t)b*EE + e)*3 + 2] > 0.5f) lst[c++] = s;
    }
    counts[tid*2 + 0] = c1;
    counts[tid*2 + 1] = c - c1;
    for (int i = c; i < LSTR; ++i) lst[i] = 0;
}

// ---------------------------------------------------------------------------
// Encoder: block = 2 nodes. Layer 1 exact fp32 on VALU per 32-wide k-slice,
// split into 3 bf16 planes in padded-stride LDS; layer 2 = bf16x3 MFMA
// (6 products ~ fp32). Tiles ordered type-major; B fragments hoisted per type.
// ---------------------------------------------------------------------------
__global__ __launch_bounds__(256, 2) void k_enc(
    const float* __restrict__ state,
    const int*   __restrict__ lists,
    const int*   __restrict__ counts,
    const float* __restrict__ W1T,   // (2,256,32) fp32
    const float* __restrict__ b1,    // (2,256)
    const unsigned short* __restrict__ W2f,
    const float* __restrict__ b2,    // (2,256)
    float* __restrict__ node_msg)
{
    const int pair = blockIdx.x % (NN/2);
    const int b    = blockIdx.x / (NN/2);
    const int n0   = pair * 2;
    const int tid  = threadIdx.x;
    const int lane = tid & 63, wave = tid >> 6;

    __shared__ __align__(16) float st[NN*DD];          // 3 KB
    __shared__ __align__(16) char  Apl[3*APL_PLANE];   // 30720 B
    __shared__ int lst_s[2][LSTR];
    __shared__ int rowsrc[128];
    __shared__ int cnt_s[4], rowbase_s[4];
    __shared__ int tgrp_s[8], tslot0_s[8];
    __shared__ int meta_s[3];   // tiles_all, rows_all, ntA

    for (int i = tid; i < NN*DD; i += 256) st[i] = state[(size_t)b*NN*DD + i];
    for (int i = tid; i < 2*LSTR; i += 256)
        lst_s[i/LSTR][i%LSTR] = lists[(b*NN + n0 + i/LSTR)*LSTR + (i%LSTR)];
    if (tid < 4) cnt_s[tid] = counts[(b*NN + n0 + (tid>>1))*2 + (tid&1)];
    __syncthreads();
    if (tid == 0) {
        // type-major order: (nd0,t0),(nd1,t0),(nd0,t1),(nd1,t1); g = 2*nd+t
        const int order[4] = {0, 2, 1, 3};
        int qb = 0, rb = 0, ntA = 0;
        for (int gg = 0; gg < 4; ++gg) {
            const int g = order[gg];
            const int tl = (cnt_s[g] + 15) >> 4;
            rowbase_s[g] = rb;
            for (int ti = 0; ti < tl; ++ti) { tgrp_s[qb+ti] = g; tslot0_s[qb+ti] = ti*16; }
            qb += tl; rb += tl*16;
            if (gg == 1) ntA = qb;
        }
        meta_s[0] = qb; meta_s[1] = rb; meta_s[2] = ntA;
    }
    __syncthreads();
    const int tiles_all = meta_s[0], rows_all = meta_s[1], ntA = meta_s[2];
    for (int r = tid; r < rows_all; r += 256) {
        const int g = tgrp_s[r >> 4];
        const int cc = cnt_s[g];
        int slot = r - rowbase_s[g];
        if (slot >= cc) slot = cc - 1;                 // pad rows: dup last edge
        const int toff = (g & 1) ? cnt_s[g & 2] : 0;
        rowsrc[r] = lst_s[g >> 1][toff + slot];
    }
    __syncthreads();

    float b2v[2][4];
    #pragma unroll
    for (int t = 0; t < 2; ++t)
        #pragma unroll
        for (int i = 0; i < 4; ++i)
            b2v[t][i] = b2[t*HH + (wave + i*4)*16 + (lane & 15)];

    f32x4 acc[8][4];
    #pragma unroll
    for (int q = 0; q < 8; ++q)
        #pragma unroll
        for (int i = 0; i < 4; ++i)
            acc[q][i] = (f32x4){0.f, 0.f, 0.f, 0.f};

    const float4* st4 = (const float4*)st;
    const int cp = tid >> 4;        // col-pair 0..15 (wave-broadcast W1T loads)
    const int rg = tid & 15;        // row 0..15

    for (int kt = 0; kt < 8; ++kt) {
        // ---- layer-1 slice: h1 cols [kt*32, kt*32+32), exact fp32, split ----
        const int c0 = kt*32 + 2*cp;
        for (int g = 0; g < 4; ++g) {
            const int cc = cnt_s[g];
            if (!cc) continue;
            const int t = g & 1, nd = g >> 1;
            const float* Wc0 = W1T + ((size_t)t*HH + c0)*32;
            const float* Wc1 = Wc0 + 32;
            float vt0 = b1[t*HH + c0], vt1 = b1[t*HH + c0 + 1];
            {
                const float4* wt0 = (const float4*)(Wc0 + 16);
                const float4* wt1 = (const float4*)(Wc1 + 16);
                #pragma unroll
                for (int f4 = 0; f4 < 4; ++f4) {
                    const float4 s4 = st4[(n0+nd)*4 + f4];
                    const float4 a = wt0[f4], bq = wt1[f4];
                    vt0 = fmaf(s4.x,a.x,  fmaf(s4.y,a.y,  fmaf(s4.z,a.z,  fmaf(s4.w,a.w,  vt0))));
                    vt1 = fmaf(s4.x,bq.x, fmaf(s4.y,bq.y, fmaf(s4.z,bq.z, fmaf(s4.w,bq.w, vt1))));
                }
            }
            float4 wa[4], wb[4];
            #pragma unroll
            for (int f4 = 0; f4 < 4; ++f4) {
                wa[f4] = ((const float4*)Wc0)[f4];
                wb[f4] = ((const float4*)Wc1)[f4];
            }
            const int rbase = rowbase_s[g];
            const int rend  = rbase + (((cc + 15) >> 4) << 4);
            for (int r = rbase + rg; r < rend; r += 16) {
                const int src = rowsrc[r];
                float u0 = vt0, u1 = vt1;
                #pragma unroll
                for (int f4 = 0; f4 < 4; ++f4) {
                    const float4 s4 = st4[src*4 + f4];
                    u0 = fmaf(s4.x,wa[f4].x, fmaf(s4.y,wa[f4].y, fmaf(s4.z,wa[f4].z, fmaf(s4.w,wa[f4].w, u0))));
                    u1 = fmaf(s4.x,wb[f4].x, fmaf(s4.y,wb[f4].y, fmaf(s4.z,wb[f4].z, fmaf(s4.w,wb[f4].w, u1))));
                }
                u0 = fmaxf(u0, 0.f); u1 = fmaxf(u1, 0.f);
                const unsigned short a0 = f2bf(u0); const float e0 = u0 - bf2f(a0);
                const unsigned short a1 = f2bf(e0); const float e1 = e0 - bf2f(a1);
                const unsigned short a2 = f2bf(e1);
                const unsigned short q0 = f2bf(u1); const float f0 = u1 - bf2f(q0);
                const unsigned short q1 = f2bf(f0); const float f1 = f0 - bf2f(q1);
                const unsigned short q2 = f2bf(f1);
                char* p0 = Apl + r*APL_STRIDE + cp*4;   // linear, padded stride
                *(unsigned*)(p0)               = (unsigned)a0 | ((unsigned)q0 << 16);
                *(unsigned*)(p0 + APL_PLANE)   = (unsigned)a1 | ((unsigned)q1 << 16);
                *(unsigned*)(p0 + 2*APL_PLANE) = (unsigned)a2 | ((unsigned)q2 << 16);
            }
        }
        __syncthreads();

        // ---- MFMA phase: B hoisted per type; A from padded-stride LDS ----
        const int abase = (lane & 15)*APL_STRIDE + (lane >> 4)*16;
        if (ntA > 0) {
            short8 Bf[4][3];
            #pragma unroll
            for (int i = 0; i < 4; ++i)
                #pragma unroll
                for (int p = 0; p < 3; ++p)
                    Bf[i][p] = *(const short8*)(W2f + ((size_t)p*65536
                                 + (size_t)kt*8192 + (wave + i*4)*512 + lane*8));
            #pragma unroll
            for (int q = 0; q < 8; ++q) {
                if (q < ntA) {
                    short8 Af[3];
                    const char* ap = Apl + q*16*APL_STRIDE + abase;
                    #pragma unroll
                    for (int p = 0; p < 3; ++p)
                        Af[p] = *(const short8*)(ap + p*APL_PLANE);
                    #pragma unroll
                    for (int i = 0; i < 4; ++i) {
                        f32x4 a = acc[q][i];
                        a = __builtin_amdgcn_mfma_f32_16x16x32_bf16(Af[2], Bf[i][0], a, 0, 0, 0);
                        a = __builtin_amdgcn_mfma_f32_16x16x32_bf16(Af[1], Bf[i][1], a, 0, 0, 0);
                        a = __builtin_amdgcn_mfma_f32_16x16x32_bf16(Af[0], Bf[i][2], a, 0, 0, 0);
                        a = __builtin_amdgcn_mfma_f32_16x16x32_bf16(Af[1], Bf[i][0], a, 0, 0, 0);
                        a = __builtin_amdgcn_mfma_f32_16x16x32_bf16(Af[0], Bf[i][1], a, 0, 0, 0);
                        a = __builtin_amdgcn_mfma_f32_16x16x32_bf16(Af[0], Bf[i][0], a, 0, 0, 0);
                        acc[q][i] = a;
                    }
                }
            }
        }
        if (tiles_all > ntA) {
            short8 Bf[4][3];
            #pragma unroll
            for (int i = 0; i < 4; ++i)
                #pragma unroll
                for (int p = 0; p < 3; ++p)
                    Bf[i][p] = *(const short8*)(W2f + ((size_t)(3+p)*65536
                                 + (size_t)kt*8192 + (wave + i*4)*512 + lane*8));
            #pragma unroll
            for (int q = 0; q < 8; ++q) {
                if (q >= ntA && q < tiles_all) {
                    short8 Af[3];
                    const char* ap = Apl + q*16*APL_STRIDE + abase;
                    #pragma unroll
                    for (int p = 0; p < 3; ++p)
                        Af[p] = *(const short8*)(ap + p*APL_PLANE);
                    #pragma unroll
                    for (int i = 0; i < 4; ++i) {
                        f32x4 a = acc[q][i];
                        a = __builtin_amdgcn_mfma_f32_16x16x32_bf16(Af[2], Bf[i][0], a, 0, 0, 0);
                        a = __builtin_amdgcn_mfma_f32_16x16x32_bf16(Af[1], Bf[i][1], a, 0, 0, 0);
                        a = __builtin_amdgcn_mfma_f32_16x16x32_bf16(Af[0], Bf[i][2], a, 0, 0, 0);
                        a = __builtin_amdgcn_mfma_f32_16x16x32_bf16(Af[1], Bf[i][0], a, 0, 0, 0);
                        a = __builtin_amdgcn_mfma_f32_16x16x32_bf16(Af[0], Bf[i][1], a, 0, 0, 0);
                        a = __builtin_amdgcn_mfma_f32_16x16x32_bf16(Af[0], Bf[i][0], a, 0, 0, 0);
                        acc[q][i] = a;
                    }
                }
            }
        }
        __syncthreads();
    }

    // ---- readout: relu(acc + b2) over active slots, shfl-reduce, store ----
    float part[4][2];
    #pragma unroll
    for (int i = 0; i < 4; ++i) { part[i][0] = 0.f; part[i][1] = 0.f; }
    #pragma unroll
    for (int q = 0; q < 8; ++q) {
        if (q < tiles_all) {
            const int g = tgrp_s[q], t = g & 1, nd = g >> 1;
            const int lim = cnt_s[g] - tslot0_s[q];
            #pragma unroll
            for (int i = 0; i < 4; ++i) {
                #pragma unroll
                for (int rr = 0; rr < 4; ++rr) {
                    const int slot = (lane >> 4)*4 + rr;
                    if (slot < lim)
                        part[i][nd] += fmaxf(acc[q][i][rr] + b2v[t][i], 0.f);
                }
            }
        }
    }
    #pragma unroll
    for (int i = 0; i < 4; ++i) {
        #pragma unroll
        for (int nd = 0; nd < 2; ++nd) {
            float v = part[i][nd];
            v += __shfl_xor(v, 16);
            v += __shfl_xor(v, 32);
            if ((lane >> 4) == 0)
                node_msg[((size_t)(b*NN + n0 + nd))*HH + (wave + i*4)*16 + lane] = v;
        }
    }
}

// ---------------------------------------------------------------------------
// Decoder: unchanged from R2 (passing).
// ---------------------------------------------------------------------------
__global__ __launch_bounds__(128, 3) void k_dec(
    float* __restrict__ state,
    const float* __restrict__ node_msg,
    const float* __restrict__ W1, const float* __restrict__ b1,
    const float* __restrict__ W2, const float* __restrict__ b2,
    const float* __restrict__ W3, const float* __restrict__ b3,
    float* __restrict__ out, int step)
{
    const int b    = blockIdx.x / 12;
    const int row0 = (blockIdx.x % 12) * 4;
    const int c    = threadIdx.x, c2 = c + 128;

    __shared__ float in_s[4][272];
    __shared__ float d1[4][HH];

    for (int i = threadIdx.x; i < 4*272; i += 128) {
        const int m = i / 272, k = i % 272;
        const int r = row0 + m;
        in_s[m][k] = (k < DD)
            ? state[((size_t)b*NN + r)*DD + k]
            : node_msg[((size_t)b*NN + r)*HH + (k - DD)];
    }
    __syncthreads();

    float a0[4], a1[4];
    {
        const float bb0 = b1[c], bb1 = b1[c2];
        #pragma unroll
        for (int m = 0; m < 4; ++m) { a0[m] = bb0; a1[m] = bb1; }
        #pragma unroll 2
        for (int k4 = 0; k4 < 68; ++k4) {
            const float* wr = W1 + (k4*4)*HH;
            const float w00=wr[c],      w01=wr[c2];
            const float w10=wr[HH+c],   w11=wr[HH+c2];
            const float w20=wr[2*HH+c], w21=wr[2*HH+c2];
            const float w30=wr[3*HH+c], w31=wr[3*HH+c2];
            #pragma unroll
            for (int m = 0; m < 4; ++m) {
                const float4 h = *(const float4*)&in_s[m][k4*4];
                a0[m] = fmaf(h.x,w00, fmaf(h.y,w10, fmaf(h.z,w20, fmaf(h.w,w30, a0[m]))));
                a1[m] = fmaf(h.x,w01, fmaf(h.y,w11, fmaf(h.z,w21, fmaf(h.w,w31, a1[m]))));
            }
        }
        #pragma unroll
        for (int m = 0; m < 4; ++m) {
            d1[m][c]  = fmaxf(a0[m], 0.f);
            d1[m][c2] = fmaxf(a1[m], 0.f);
        }
    }
    __syncthreads();
    {
        const float bb0 = b2[c], bb1 = b2[c2];
        #pragma unroll
        for (int m = 0; m < 4; ++m) { a0[m] = bb0; a1[m] = bb1; }
        #pragma unroll 2
        for (int k4 = 0; k4 < 64; ++k4) {
            const float* wr = W2 + (k4*4)*HH;
            const float w00=wr[c],      w01=wr[c2];
            const float w10=wr[HH+c],   w11=wr[HH+c2];
            const float w20=wr[2*HH+c], w21=wr[2*HH+c2];
            const float w30=wr[3*HH+c], w31=wr[3*HH+c2];
            #pragma unroll
            for (int m = 0; m < 4; ++m) {
                const float4 h = *(const float4*)&d1[m][k4*4];
                a0[m] = fmaf(h.x,w00, fmaf(h.y,w10, fmaf(h.z,w20, fmaf(h.w,w30, a0[m]))));
                a1[m] = fmaf(h.x,w01, fmaf(h.y,w11, fmaf(h.z,w21, fmaf(h.w,w31, a1[m]))));
            }
        }
        __syncthreads();
        #pragma unroll
        for (int m = 0; m < 4; ++m) {
            in_s[m][c]  = fmaxf(a0[m], 0.f);
            in_s[m][c2] = fmaxf(a1[m], 0.f);
        }
    }
    __syncthreads();
    if (threadIdx.x < 64) {
        const int m = threadIdx.x >> 4, cc = threadIdx.x & 15;
        float a = b3[cc];
        #pragma unroll 4
        for (int k4 = 0; k4 < 64; ++k4) {
            const float4 h = *(const float4*)&in_s[m][k4*4];
            a += h.x*W3[(k4*4+0)*16+cc] + h.y*W3[(k4*4+1)*16+cc]
               + h.z*W3[(k4*4+2)*16+cc] + h.w*W3[(k4*4+3)*16+cc];
        }
        const int r = row0 + m;
        const float v = state[((size_t)b*NN + r)*DD + cc] + a;
        state[((size_t)b*NN + r)*DD + cc] = v;
        out[(((size_t)b*NPRED + step)*NN + r)*DD + cc] = v;
    }
}

// ---------------------------------------------------------------------------
extern "C" void kernel_launch(void* const* d_in, const int* in_sizes, int n_in,
                              void* d_out, int out_size, void* d_ws, size_t ws_size,
                              hipStream_t stream)
{
    const float* time_segs  = (const float*)d_in[0];
    const float* edge_types = (const float*)d_in[1];
    const float* enc_W1 = (const float*)d_in[4];
    const float* enc_b1 = (const float*)d_in[5];
    const float* enc_W2 = (const float*)d_in[6];
    const float* enc_b2 = (const float*)d_in[7];
    const float* dec_W1 = (const float*)d_in[8];
    const float* dec_b1 = (const float*)d_in[9];
    const float* dec_W2 = (const float*)d_in[10];
    const float* dec_b2 = (const float*)d_in[11];
    const float* out_W  = (const float*)d_in[12];
    const float* out_b  = (const float*)d_in[13];
    float* out = (float*)d_out;

    float* state    = (float*)d_ws;                    // 24576 f
    float* node_msg = state + BB*NN*DD;                // 393216 f
    float* W1T      = node_msg + BB*NN*HH;             // 16384 f
    unsigned short* W2f = (unsigned short*)(W1T + 2*HH*32);   // 393216 us
    int*   lists    = (int*)(W2f + 2*3*65536);         // 86016 i
    int*   counts   = lists + BB*NN*LSTR;              // 3072 i

    k_setup<<<6, 256, 0, stream>>>(time_segs, edge_types, enc_W1, enc_W2,
                                   state, W1T, W2f, lists, counts);
    for (int stp = 0; stp < NPRED; ++stp) {
        k_enc<<<BB*(NN/2), 256, 0, stream>>>(state, lists, counts,
                                             W1T, enc_b1, W2f, enc_b2, node_msg);
        k_dec<<<BB*12, 128, 0, stream>>>(state, node_msg,
                                         dec_W1, dec_b1, dec_W2, dec_b2,
                                         out_W, out_b, out, stp);
    }
}

// Round 5
// 1149.448 us; speedup vs baseline: 2.1572x; 1.1992x over previous
//
#include <hip/hip_runtime.h>

#define NN    48
#define DD    16
#define HH    256
#define EE    2256
#define BB    32
#define NPRED 8
#define LSTR  56
#define STP   20                     // state LDS row stride (floats) — kills gather conflicts
#define ROWB  80                     // Apl row stride bytes (5x16B, bijective, ~2-way banks)
#define TMAX  7                      // packed tiles/block <= 7 (proof: 8 needs >=98 rows > 94)
#define APL_PLANE (TMAX*16*ROWB)     // 8960 B per plane

typedef __attribute__((ext_vector_type(4))) float f32x4;
typedef __attribute__((ext_vector_type(8))) short short8;

__device__ __forceinline__ float bf2f(unsigned short h) {
    union { unsigned u; float f; } v; v.u = ((unsigned)h) << 16; return v.f;
}
__device__ __forceinline__ unsigned short f2bf(float x) {
    union { float f; unsigned u; } v; v.f = x;
    unsigned r = v.u + 0x7fffu + ((v.u >> 16) & 1u);
    return (unsigned short)(r >> 16);
}

// ---------------------------------------------------------------------------
// Setup: state copy, W1 transpose, type-grouped edge lists, W2 split into
// 3 bf16 planes in MFMA B-fragment order (unchanged from R4 — verified).
// ---------------------------------------------------------------------------
__global__ __launch_bounds__(256) void k_setup(
    const float* __restrict__ time_segs,
    const float* __restrict__ edge_types,
    const float* __restrict__ W1,      // (2,32,256)
    const float* __restrict__ W2,      // (2,256,256)
    float* __restrict__ state,
    float* __restrict__ W1T,           // (2,256,32)
    unsigned short* __restrict__ W2f,  // 393216
    int* __restrict__ lists,
    int* __restrict__ counts)
{
    const int tid = blockIdx.x * 256 + threadIdx.x;   // 0..1535
    for (int i = tid; i < BB*NN*DD; i += BB*NN)
        state[i] = time_segs[i];
    for (int i = tid; i < 2*HH*32; i += BB*NN) {
        const int t = i >> 13, r = i & 8191, h = r >> 5, f = r & 31;
        W1T[i] = W1[(t*32 + f)*HH + h];
    }
    for (int i = tid; i < 2*8*16*64*8; i += BB*NN) {
        const int j  = i & 7, l = (i >> 3) & 63, nt = (i >> 9) & 15;
        const int kt = (i >> 13) & 7, t = (i >> 16) & 1;
        const int k = kt*32 + ((l >> 4) << 3) + j;
        const int n = nt*16 + (l & 15);
        const float w = W2[((size_t)t*HH + k)*HH + n];
        const unsigned short h0 = f2bf(w);  const float r1 = w  - bf2f(h0);
        const unsigned short h1 = f2bf(r1); const float r2 = r1 - bf2f(h1);
        const unsigned short h2 = f2bf(r2);
        const size_t rest = (size_t)kt*8192 + nt*512 + l*8 + j;
        W2f[(size_t)(t*3+0)*65536 + rest] = h0;
        W2f[(size_t)(t*3+1)*65536 + rest] = h1;
        W2f[(size_t)(t*3+2)*65536 + rest] = h2;
    }
    const int b = tid / NN;
    const int n = tid % NN;
    int* lst = lists + tid * LSTR;
    int c = 0;
    for (int s = 0; s < NN; ++s) {
        if (s == n) continue;
        const int e = s * 47 + (n > s ? n - 1 : n);
        if (edge_types[((size_t)b*EE + e)*3 + 1] > 0.5f) lst[c++] = s;
    }
    const int c1 = c;
    for (int s = 0; s < NN; ++s) {
        if (s == n) continue;
        const int e = s * 47 + (n > s ? n - 1 : n);
        if (edge_types[((size_t)b*EE + e)*3 + 2] > 0.5f) lst[c++] = s;
    }
    counts[tid*2 + 0] = c1;
    counts[tid*2 + 1] = c - c1;
    for (int i = c; i < LSTR; ++i) lst[i] = 0;
}

// ---------------------------------------------------------------------------
// Encoder: block = 2 nodes, edges PACKED per type (tiles type-pure, per-row
// node mask at readout) -> <=7 m-tiles -> acc[7][4] = 112 VGPR, no spills.
// Layer 1 exact fp32 VALU per 32-col k-slice -> 3 bf16 planes in LDS;
// layer 2 = bf16x3 MFMA (6 products ~ fp32 accuracy).
// ---------------------------------------------------------------------------
__global__ __launch_bounds__(256, 2) void k_enc(
    const float* __restrict__ state,
    const int*   __restrict__ lists,
    const int*   __restrict__ counts,
    const float* __restrict__ W1T,   // (2,256,32) fp32
    const float* __restrict__ b1,    // (2,256)
    const unsigned short* __restrict__ W2f,
    const float* __restrict__ b2,    // (2,256)
    float* __restrict__ node_msg)
{
    const int pair = blockIdx.x % (NN/2);
    const int b    = blockIdx.x / (NN/2);
    const int n0   = pair * 2;
    const int tid  = threadIdx.x;
    const int lane = tid & 63, wave = tid >> 6;

    __shared__ __align__(16) float st[NN*STP];         // 3.84 KB, padded rows
    __shared__ __align__(16) char  Apl[3*APL_PLANE];   // 26.9 KB
    __shared__ int lst_s[2][LSTR];
    __shared__ int rowinfo[TMAX*16];                   // src | g<<8 (g=t*2+nd, 4=pad)
    __shared__ int cnt_s[4];

    for (int i = tid; i < NN*DD; i += 256)
        st[(i >> 4)*STP + (i & 15)] = state[(size_t)b*NN*DD + i];
    for (int i = tid; i < 2*LSTR; i += 256)
        lst_s[i/LSTR][i%LSTR] = lists[(b*NN + n0 + i/LSTR)*LSTR + (i%LSTR)];
    if (tid < 4) cnt_s[tid] = counts[(b*NN + n0 + (tid>>1))*2 + (tid&1)];
    __syncthreads();

    const int c00 = cnt_s[0], c10 = cnt_s[1], c01 = cnt_s[2], c11 = cnt_s[3];
    const int tA  = c00 + c01, tB = c10 + c11;
    const int tAt = (tA + 15) >> 4, tBt = (tB + 15) >> 4;
    const int tiles = tAt + tBt;

    for (int r = tid; r < tiles*16; r += 256) {
        int g, src;
        if (r < tAt*16) {
            if (r < c00)     { src = lst_s[0][r];            g = 0; }
            else if (r < tA) { src = lst_s[1][r - c00];      g = 1; }
            else             { src = c00 ? lst_s[0][0] : lst_s[1][0]; g = 4; }
        } else {
            const int s = r - tAt*16;
            if (s < c10)     { src = lst_s[0][c00 + s];      g = 2; }
            else if (s < tB) { src = lst_s[1][c01 + s - c10]; g = 3; }
            else             { src = c10 ? lst_s[0][c00] : lst_s[1][c01]; g = 4; }
        }
        rowinfo[r] = src | (g << 8);
    }
    __syncthreads();

    float b2v[2][4];
    #pragma unroll
    for (int t = 0; t < 2; ++t)
        #pragma unroll
        for (int i = 0; i < 4; ++i)
            b2v[t][i] = b2[t*HH + (wave + i*4)*16 + (lane & 15)];

    f32x4 acc[TMAX][4];
    #pragma unroll
    for (int q = 0; q < TMAX; ++q)
        #pragma unroll
        for (int i = 0; i < 4; ++i)
            acc[q][i] = (f32x4){0.f, 0.f, 0.f, 0.f};

    const int cp = tid >> 4;   // col-pair 0..15 (16 lanes share -> bcast weights)
    const int rg = tid & 15;   // row 0..15

    for (int kt = 0; kt < 8; ++kt) {
        const int col0 = kt*32 + 2*cp;
        // ---- layer-1 slice: exact fp32, split to 3 bf16 planes ----
        int secBase = 0;
        #pragma unroll
        for (int t = 0; t < 2; ++t) {
            const int secT = t ? tBt : tAt;
            if (secT) {
                const float* W1c0 = W1T + ((size_t)t*HH + col0)*32;
                const float* W1c1 = W1c0 + 32;
                float4 wa[4], wb[4];
                #pragma unroll
                for (int f4 = 0; f4 < 4; ++f4) {
                    wa[f4] = ((const float4*)W1c0)[f4];
                    wb[f4] = ((const float4*)W1c1)[f4];
                }
                float vtA0 = b1[t*HH + col0], vtA1 = b1[t*HH + col0 + 1];
                float vtB0 = vtA0, vtB1 = vtA1;
                #pragma unroll
                for (int f4 = 0; f4 < 4; ++f4) {
                    const float4 w0 = ((const float4*)(W1c0 + 16))[f4];
                    const float4 w1 = ((const float4*)(W1c1 + 16))[f4];
                    const float4 s0 = *(const float4*)(st + n0*STP + f4*4);
                    const float4 s1 = *(const float4*)(st + (n0+1)*STP + f4*4);
                    vtA0 = fmaf(s0.x,w0.x, fmaf(s0.y,w0.y, fmaf(s0.z,w0.z, fmaf(s0.w,w0.w, vtA0))));
                    vtA1 = fmaf(s0.x,w1.x, fmaf(s0.y,w1.y, fmaf(s0.z,w1.z, fmaf(s0.w,w1.w, vtA1))));
                    vtB0 = fmaf(s1.x,w0.x, fmaf(s1.y,w0.y, fmaf(s1.z,w0.z, fmaf(s1.w,w0.w, vtB0))));
                    vtB1 = fmaf(s1.x,w1.x, fmaf(s1.y,w1.y, fmaf(s1.z,w1.z, fmaf(s1.w,w1.w, vtB1))));
                }
                const int rend = secBase + secT*16;
                for (int r = secBase + rg; r < rend; r += 16) {
                    const int info = rowinfo[r];
                    const int src  = info & 255;
                    const bool nd1 = (info & 256) != 0;
                    float u0 = nd1 ? vtB0 : vtA0;
                    float u1 = nd1 ? vtB1 : vtA1;
                    const float* srow = st + src*STP;
                    #pragma unroll
                    for (int f4 = 0; f4 < 4; ++f4) {
                        const float4 s4 = *(const float4*)(srow + f4*4);
                        u0 = fmaf(s4.x,wa[f4].x, fmaf(s4.y,wa[f4].y, fmaf(s4.z,wa[f4].z, fmaf(s4.w,wa[f4].w, u0))));
                        u1 = fmaf(s4.x,wb[f4].x, fmaf(s4.y,wb[f4].y, fmaf(s4.z,wb[f4].z, fmaf(s4.w,wb[f4].w, u1))));
                    }
                    u0 = fmaxf(u0, 0.f); u1 = fmaxf(u1, 0.f);
                    const unsigned short a0 = f2bf(u0); const float e0 = u0 - bf2f(a0);
                    const unsigned short a1 = f2bf(e0); const float e1 = e0 - bf2f(a1);
                    const unsigned short a2 = f2bf(e1);
                    const unsigned short q0 = f2bf(u1); const float f0 = u1 - bf2f(q0);
                    const unsigned short q1 = f2bf(f0); const float f1 = f0 - bf2f(q1);
                    const unsigned short q2 = f2bf(f1);
                    char* p0 = Apl + r*ROWB + cp*4;
                    *(unsigned*)(p0)               = (unsigned)a0 | ((unsigned)q0 << 16);
                    *(unsigned*)(p0 + APL_PLANE)   = (unsigned)a1 | ((unsigned)q1 << 16);
                    *(unsigned*)(p0 + 2*APL_PLANE) = (unsigned)a2 | ((unsigned)q2 << 16);
                }
            }
            secBase += secT*16;
        }
        __syncthreads();

        // ---- MFMA: type-pure sections, B hoisted per section ----
        const int abase = (lane & 15)*ROWB + (lane >> 4)*16;
        if (tAt) {
            short8 Bf[4][3];
            #pragma unroll
            for (int i = 0; i < 4; ++i)
                #pragma unroll
                for (int p = 0; p < 3; ++p)
                    Bf[i][p] = *(const short8*)(W2f + ((size_t)p*65536
                                 + (size_t)kt*8192 + (wave + i*4)*512 + lane*8));
            #pragma unroll
            for (int q = 0; q < TMAX; ++q) {
                if (q < tAt) {
                    short8 Af[3];
                    const char* ap = Apl + q*16*ROWB + abase;
                    #pragma unroll
                    for (int p = 0; p < 3; ++p)
                        Af[p] = *(const short8*)(ap + p*APL_PLANE);
                    #pragma unroll
                    for (int i = 0; i < 4; ++i) {
                        f32x4 a = acc[q][i];
                        a = __builtin_amdgcn_mfma_f32_16x16x32_bf16(Af[2], Bf[i][0], a, 0, 0, 0);
                        a = __builtin_amdgcn_mfma_f32_16x16x32_bf16(Af[1], Bf[i][1], a, 0, 0, 0);
                        a = __builtin_amdgcn_mfma_f32_16x16x32_bf16(Af[0], Bf[i][2], a, 0, 0, 0);
                        a = __builtin_amdgcn_mfma_f32_16x16x32_bf16(Af[1], Bf[i][0], a, 0, 0, 0);
                        a = __builtin_amdgcn_mfma_f32_16x16x32_bf16(Af[0], Bf[i][1], a, 0, 0, 0);
                        a = __builtin_amdgcn_mfma_f32_16x16x32_bf16(Af[0], Bf[i][0], a, 0, 0, 0);
                        acc[q][i] = a;
                    }
                }
            }
        }
        if (tBt) {
            short8 Bf[4][3];
            #pragma unroll
            for (int i = 0; i < 4; ++i)
                #pragma unroll
                for (int p = 0; p < 3; ++p)
                    Bf[i][p] = *(const short8*)(W2f + ((size_t)(3+p)*65536
                                 + (size_t)kt*8192 + (wave + i*4)*512 + lane*8));
            #pragma unroll
            for (int q = 0; q < TMAX; ++q) {
                if (q >= tAt && q < tiles) {
                    short8 Af[3];
                    const char* ap = Apl + q*16*ROWB + abase;
                    #pragma unroll
                    for (int p = 0; p < 3; ++p)
                        Af[p] = *(const short8*)(ap + p*APL_PLANE);
                    #pragma unroll
                    for (int i = 0; i < 4; ++i) {
                        f32x4 a = acc[q][i];
                        a = __builtin_amdgcn_mfma_f32_16x16x32_bf16(Af[2], Bf[i][0], a, 0, 0, 0);
                        a = __builtin_amdgcn_mfma_f32_16x16x32_bf16(Af[1], Bf[i][1], a, 0, 0, 0);
                        a = __builtin_amdgcn_mfma_f32_16x16x32_bf16(Af[0], Bf[i][2], a, 0, 0, 0);
                        a = __builtin_amdgcn_mfma_f32_16x16x32_bf16(Af[1], Bf[i][0], a, 0, 0, 0);
                        a = __builtin_amdgcn_mfma_f32_16x16x32_bf16(Af[0], Bf[i][1], a, 0, 0, 0);
                        a = __builtin_amdgcn_mfma_f32_16x16x32_bf16(Af[0], Bf[i][0], a, 0, 0, 0);
                        acc[q][i] = a;
                    }
                }
            }
        }
        __syncthreads();
    }

    // ---- readout: relu(acc+b2), per-row node mask, shfl-reduce, store ----
    float p0[4], p1[4];
    #pragma unroll
    for (int i = 0; i < 4; ++i) { p0[i] = 0.f; p1[i] = 0.f; }
    #pragma unroll
    for (int q = 0; q < TMAX; ++q) {
        if (q < tiles) {
            const bool secB = (q >= tAt);
            int gv[4];
            #pragma unroll
            for (int rr = 0; rr < 4; ++rr)
                gv[rr] = rowinfo[q*16 + (lane >> 4)*4 + rr] >> 8;
            #pragma unroll
            for (int i = 0; i < 4; ++i) {
                const float bias = secB ? b2v[1][i] : b2v[0][i];
                #pragma unroll
                for (int rr = 0; rr < 4; ++rr) {
                    const float v = fmaxf(acc[q][i][rr] + bias, 0.f);
                    const bool valid = gv[rr] < 4;
                    p0[i] += (valid && !(gv[rr] & 1)) ? v : 0.f;
                    p1[i] += (valid &&  (gv[rr] & 1)) ? v : 0.f;
                }
            }
        }
    }
    #pragma unroll
    for (int i = 0; i < 4; ++i) {
        float v0 = p0[i], v1 = p1[i];
        v0 += __shfl_xor(v0, 16); v0 += __shfl_xor(v0, 32);
        v1 += __shfl_xor(v1, 16); v1 += __shfl_xor(v1, 32);
        if ((lane >> 4) == 0) {
            node_msg[((size_t)(b*NN + n0  ))*HH + (wave + i*4)*16 + lane] = v0;
            node_msg[((size_t)(b*NN + n0+1))*HH + (wave + i*4)*16 + lane] = v1;
        }
    }
}

// ---------------------------------------------------------------------------
// Decoder: unchanged (passing, ~12 us/step).
// ---------------------------------------------------------------------------
__global__ __launch_bounds__(128, 3) void k_dec(
    float* __restrict__ state,
    const float* __restrict__ node_msg,
    const float* __restrict__ W1, const float* __restrict__ b1,
    const float* __restrict__ W2, const float* __restrict__ b2,
    const float* __restrict__ W3, const float* __restrict__ b3,
    float* __restrict__ out, int step)
{
    const int b    = blockIdx.x / 12;
    const int row0 = (blockIdx.x % 12) * 4;
    const int c    = threadIdx.x, c2 = c + 128;

    __shared__ float in_s[4][272];
    __shared__ float d1[4][HH];

    for (int i = threadIdx.x; i < 4*272; i += 128) {
        const int m = i / 272, k = i % 272;
        const int r = row0 + m;
        in_s[m][k] = (k < DD)
            ? state[((size_t)b*NN + r)*DD + k]
            : node_msg[((size_t)b*NN + r)*HH + (k - DD)];
    }
    __syncthreads();

    float a0[4], a1[4];
    {
        const float bb0 = b1[c], bb1 = b1[c2];
        #pragma unroll
        for (int m = 0; m < 4; ++m) { a0[m] = bb0; a1[m] = bb1; }
        #pragma unroll 2
        for (int k4 = 0; k4 < 68; ++k4) {
            const float* wr = W1 + (k4*4)*HH;
            const float w00=wr[c],      w01=wr[c2];
            const float w10=wr[HH+c],   w11=wr[HH+c2];
            const float w20=wr[2*HH+c], w21=wr[2*HH+c2];
            const float w30=wr[3*HH+c], w31=wr[3*HH+c2];
            #pragma unroll
            for (int m = 0; m < 4; ++m) {
                const float4 h = *(const float4*)&in_s[m][k4*4];
                a0[m] = fmaf(h.x,w00, fmaf(h.y,w10, fmaf(h.z,w20, fmaf(h.w,w30, a0[m]))));
                a1[m] = fmaf(h.x,w01, fmaf(h.y,w11, fmaf(h.z,w21, fmaf(h.w,w31, a1[m]))));
            }
        }
        #pragma unroll
        for (int m = 0; m < 4; ++m) {
            d1[m][c]  = fmaxf(a0[m], 0.f);
            d1[m][c2] = fmaxf(a1[m], 0.f);
        }
    }
    __syncthreads();
    {
        const float bb0 = b2[c], bb1 = b2[c2];
        #pragma unroll
        for (int m = 0; m < 4; ++m) { a0[m] = bb0; a1[m] = bb1; }
        #pragma unroll 2
        for (int k4 = 0; k4 < 64; ++k4) {
            const float* wr = W2 + (k4*4)*HH;
            const float w00=wr[c],      w01=wr[c2];
            const float w10=wr[HH+c],   w11=wr[HH+c2];
            const float w20=wr[2*HH+c], w21=wr[2*HH+c2];
            const float w30=wr[3*HH+c], w31=wr[3*HH+c2];
            #pragma unroll
            for (int m = 0; m < 4; ++m) {
                const float4 h = *(const float4*)&d1[m][k4*4];
                a0[m] = fmaf(h.x,w00, fmaf(h.y,w10, fmaf(h.z,w20, fmaf(h.w,w30, a0[m]))));
                a1[m] = fmaf(h.x,w01, fmaf(h.y,w11, fmaf(h.z,w21, fmaf(h.w,w31, a1[m]))));
            }
        }
        __syncthreads();
        #pragma unroll
        for (int m = 0; m < 4; ++m) {
            in_s[m][c]  = fmaxf(a0[m], 0.f);
            in_s[m][c2] = fmaxf(a1[m], 0.f);
        }
    }
    __syncthreads();
    if (threadIdx.x < 64) {
        const int m = threadIdx.x >> 4, cc = threadIdx.x & 15;
        float a = b3[cc];
        #pragma unroll 4
        for (int k4 = 0; k4 < 64; ++k4) {
            const float4 h = *(const float4*)&in_s[m][k4*4];
            a += h.x*W3[(k4*4+0)*16+cc] + h.y*W3[(k4*4+1)*16+cc]
               + h.z*W3[(k4*4+2)*16+cc] + h.w*W3[(k4*4+3)*16+cc];
        }
        const int r = row0 + m;
        const float v = state[((size_t)b*NN + r)*DD + cc] + a;
        state[((size_t)b*NN + r)*DD + cc] = v;
        out[(((size_t)b*NPRED + step)*NN + r)*DD + cc] = v;
    }
}

// ---------------------------------------------------------------------------
extern "C" void kernel_launch(void* const* d_in, const int* in_sizes, int n_in,
                              void* d_out, int out_size, void* d_ws, size_t ws_size,
                              hipStream_t stream)
{
    const float* time_segs  = (const float*)d_in[0];
    const float* edge_types = (const float*)d_in[1];
    const float* enc_W1 = (const float*)d_in[4];
    const float* enc_b1 = (const float*)d_in[5];
    const float* enc_W2 = (const float*)d_in[6];
    const float* enc_b2 = (const float*)d_in[7];
    const float* dec_W1 = (const float*)d_in[8];
    const float* dec_b1 = (const float*)d_in[9];
    const float* dec_W2 = (const float*)d_in[10];
    const float* dec_b2 = (const float*)d_in[11];
    const float* out_W  = (const float*)d_in[12];
    const float* out_b  = (const float*)d_in[13];
    float* out = (float*)d_out;

    float* state    = (float*)d_ws;                    // 24576 f
    float* node_msg = state + BB*NN*DD;                // 393216 f
    float* W1T      = node_msg + BB*NN*HH;             // 16384 f
    unsigned short* W2f = (unsigned short*)(W1T + 2*HH*32);   // 393216 us
    int*   lists    = (int*)(W2f + 2*3*65536);         // 86016 i
    int*   counts   = lists + BB*NN*LSTR;              // 3072 i

    k_setup<<<6, 256, 0, stream>>>(time_segs, edge_types, enc_W1, enc_W2,
                                   state, W1T, W2f, lists, counts);
    for (int stp = 0; stp < NPRED; ++stp) {
        k_enc<<<BB*(NN/2), 256, 0, stream>>>(state, lists, counts,
                                             W1T, enc_b1, W2f, enc_b2, node_msg);
        k_dec<<<BB*12, 128, 0, stream>>>(state, node_msg,
                                         dec_W1, dec_b1, dec_W2, dec_b2,
                                         out_W, out_b, out, stp);
    }
}